// Round 6
// baseline (2182.338 us; speedup 1.0000x reference)
//
#include <hip/hip_runtime.h>
#include <cmath>

#define HW 256
#define NIMG 48
#define NCH 3
#define NPLANE (NIMG * NCH)
#define STRIP 32
#define NSTRIP (HW / STRIP)           // 8
#define NBLOCKS (NPLANE * NSTRIP)     // 1152
#define NITER (STRIP + 10)            // 42 input rows per block
#define NCHUNK 11                     // 11 chunks x 4 rows = 44 slots, 42 used

// ws doubles: ws[0]=sum dssim, ws[1]=sum |diff|, ws[2]=sum w*|diff|, ws[3]=done ctr
__global__ void zero_ws_kernel(double* ws) {
    if (threadIdx.x < 4) ws[threadIdx.x] = 0.0;
}

// ---------------------------------------------------------------------------
// Fused SSIM + L1 + weighted-L1, software-pipelined (m97-style):
//  - one block = 32-row output strip of one (n,c) plane, 42 input rows
//  - chunks of 4 rows, double-buffered LDS; per chunk:
//      issue next chunk's global float4 loads -> registers   (wave w = row w)
//      compute current chunk's 4 rows from LDS buffer A
//      ds_write prefetched regs -> buffer B   (vmcnt wait lands HERE, after
//                                              ~2700 VALU cycles of compute)
//      ONE __syncthreads  (write/read hazards on a buffer are always
//                          separated by the previous phase's barrier)
//  - separable 11x11: h-conv from LDS row (float2 (p,t) pairs, 6-pad each
//    side, 16B-aligned staging writes), v-conv via 11-slot register ring
//    with compile-time i%11 indexing (fully unrolled chunks)
//  - polygon crossings precomputed per (strip-row, edge); L1/wl1 taken from
//    the h-conv center tap; last finishing block computes the final scalar
// ---------------------------------------------------------------------------
__launch_bounds__(256, 4)
__global__ void fused_kernel(const float* __restrict__ pred,
                             const float* __restrict__ target,
                             const float* __restrict__ lmk,
                             double* __restrict__ ws,
                             float* __restrict__ out)
{
    const int plane = blockIdx.x;          // n*3 + c
    const int n     = plane / 3;
    const int r0    = blockIdx.y * STRIP;
    const int tid   = threadIdx.x;
    const int w     = tid >> 6;            // wave id 0..3 (staging row within chunk)
    const int l     = tid & 63;            // lane

    // row layout (float2 view): [0..5]=zero pad, [6..261]=cols 0..255, [262..267]=pad
    __shared__ float4 sbuf[2][4][134];     // 2 bufs x 4 rows x 268 float2
    __shared__ float  sxc[STRIP][24];      // crossing x per (out row, edge)
    __shared__ float  slm[48];
    __shared__ float  sbbs[12];
    __shared__ float  svalids[3];
    __shared__ float  red[12];

    // Gaussian weights (same fp32 math as reference)
    float g[11];
    {
        float gs = 0.f;
#pragma unroll
        for (int i = 0; i < 11; ++i) {
            float c = (float)i - 5.0f;
            g[i] = expf(-c * c / 4.5f);
            gs += g[i];
        }
#pragma unroll
        for (int i = 0; i < 11; ++i) g[i] /= gs;
    }

    const float* __restrict__ pp = pred   + (size_t)plane * (HW * HW);
    const float* __restrict__ tp = target + (size_t)plane * (HW * HW);

    // ---- prologue ----------------------------------------------------------
    if (tid < 48) slm[tid] = lmk[n * 136 + 72 + tid];

    // zero the column pads of all 8 row buffers (once)
    if (tid < 96) {
        int bi  = tid / 48;
        int rem = tid - bi * 48;
        int rw  = rem / 12;
        int p   = rem - rw * 12;          // 0..11
        int idx = (p < 6) ? p : (256 + p); // 0..5 or 262..267
        ((float2*)&sbuf[bi][rw][0])[idx] = make_float2(0.f, 0.f);
    }

    // stage chunk 0 (input iters 0..3 = rows r0-5 .. r0-2)
    {
        float4 pf = make_float4(0.f, 0.f, 0.f, 0.f);
        float4 tf = make_float4(0.f, 0.f, 0.f, 0.f);
        int r = r0 - 5 + w;
        if (r >= 0) {                      // r < HW always (r0-2 <= 222+...)
            pf = ((const float4*)(pp + (size_t)r * HW))[l];
            tf = ((const float4*)(tp + (size_t)r * HW))[l];
        }
        float4* row4 = &sbuf[0][w][0];
        row4[3 + 2 * l] = make_float4(pf.x, tf.x, pf.y, tf.y);
        row4[4 + 2 * l] = make_float4(pf.z, tf.z, pf.w, tf.w);
    }
    __syncthreads();   // slm visible

    if (tid < 3) {
        const int s0 = (tid == 0) ? 0 : (tid == 1) ? 6 : 12;
        const int L  = (tid == 2) ? 12 : 6;
        float xmn = 3e38f, xmx = -3e38f, ymn = 3e38f, ymx = -3e38f;
        for (int i = 0; i < L; ++i) {
            float px = slm[2 * (s0 + i)], py = slm[2 * (s0 + i) + 1];
            xmn = fminf(xmn, px); xmx = fmaxf(xmx, px);
            ymn = fminf(ymn, py); ymx = fmaxf(ymx, py);
        }
        xmn = floorf(xmn); xmx = floorf(xmx); ymn = floorf(ymn); ymx = floorf(ymx);
        sbbs[4 * tid + 0] = xmn; sbbs[4 * tid + 1] = xmx;
        sbbs[4 * tid + 2] = ymn; sbbs[4 * tid + 3] = ymx;
        svalids[tid] = (xmn >= 0.f && ymn >= 0.f && xmx < 256.f && ymx < 256.f) ? 1.f : 0.f;
    }

#pragma unroll
    for (int u = 0; u < 3; ++u) {
        int idx = tid + 256 * u;
        if (idx < STRIP * 24) {
            int r = idx / 24, e = idx - r * 24;
            float Y = (float)(r0 + r);
            const int s0 = (e < 6) ? 0 : (e < 12) ? 6 : 12;
            const int L  = (e < 12) ? 6 : 12;
            int il = e - s0;
            int i2 = (il + 1 == L) ? 0 : il + 1;
            float x1 = slm[2 * (s0 + il)], y1 = slm[2 * (s0 + il) + 1];
            float x2 = slm[2 * (s0 + i2)], y2 = slm[2 * (s0 + i2) + 1];
            bool crossing = (y1 > Y) != (y2 > Y);
            // exact reference fp32 expression order
            float xc = (x2 - x1) * (Y - y1) / (y2 - y1 + 1e-6f) + x1;
            sxc[r][e] = crossing ? xc : -3e38f;
        }
    }
    __syncthreads();   // sxc/sbbs/svalids + chunk-0 staging visible

    // ---- main loop ---------------------------------------------------------
    float ring[11][5];
#pragma unroll
    for (int s = 0; s < 11; ++s)
#pragma unroll
        for (int q = 0; q < 5; ++q) ring[s][q] = 0.f;

    float acc = 0.f, accl1 = 0.f, acclw = 0.f;
    const float X = (float)tid;

#pragma unroll
    for (int c = 0; c < NCHUNK; ++c) {
        // issue prefetch for chunk c+1 (wave w stages input iter 4(c+1)+w)
        float4 pf = make_float4(0.f, 0.f, 0.f, 0.f);
        float4 tf = make_float4(0.f, 0.f, 0.f, 0.f);
        const bool do_load = (c < 9) || (c == 9 && w < 2);   // iload < 42
        if (do_load) {
            int r = r0 - 5 + 4 * (c + 1) + w;
            if ((unsigned)r < (unsigned)HW) {
                pf = ((const float4*)(pp + (size_t)r * HW))[l];
                tf = ((const float4*)(tp + (size_t)r * HW))[l];
            }
        }

        // compute the 4 rows of chunk c from buffer c&1
#pragma unroll
        for (int t = 0; t < 4; ++t) {
            const int i = 4 * c + t;               // compile-time
            if (i < NITER) {
                const float2* row2 = (const float2*)&sbuf[c & 1][t][0];
                float h0 = 0.f, h1 = 0.f, h2 = 0.f, h3 = 0.f, h4 = 0.f;
                float2 center = make_float2(0.f, 0.f);
#pragma unroll
                for (int k = 0; k < 11; ++k) {
                    float2 v = row2[1 + tid + k];  // idx 6 + (tid-5) + k
                    if (k == 5) center = v;
                    float wk = g[k];
                    float wp = wk * v.x, wt = wk * v.y;
                    h0 += wp; h1 += wt;
                    h2 = fmaf(wp, v.x, h2);
                    h3 = fmaf(wt, v.y, h3);
                    h4 = fmaf(wp, v.y, h4);
                }
                ring[i % 11][0] = h0; ring[i % 11][1] = h1; ring[i % 11][2] = h2;
                ring[i % 11][3] = h3; ring[i % 11][4] = h4;

                if (i >= 5 && i < 5 + STRIP) {     // L1 + weighted L1, row r0+i-5
                    float ad = fabsf(center.x - center.y);
                    accl1 += ad;
                    float Y = (float)(r0 + i - 5);
                    float wgt = 1.f;
                    bool any0 = (svalids[0] != 0.f) && (Y >= sbbs[2])  && (Y < sbbs[3]);
                    bool any1 = (svalids[1] != 0.f) && (Y >= sbbs[6])  && (Y < sbbs[7]);
                    bool any2 = (svalids[2] != 0.f) && (Y >= sbbs[10]) && (Y < sbbs[11]);
                    if (any0 || any1 || any2) {
                        const float* xc = sxc[i - 5];
                        int cc0 = 0, cc1 = 0, cc2 = 0;
#pragma unroll
                        for (int e = 0; e < 6; ++e)   cc0 += (X < xc[e]) ? 1 : 0;
#pragma unroll
                        for (int e = 6; e < 12; ++e)  cc1 += (X < xc[e]) ? 1 : 0;
#pragma unroll
                        for (int e = 12; e < 24; ++e) cc2 += (X < xc[e]) ? 1 : 0;
                        if (any0 && (cc0 & 1) && X >= sbbs[0] && X < sbbs[1]) wgt += 3.f;
                        if (any1 && (cc1 & 1) && X >= sbbs[4] && X < sbbs[5]) wgt += 3.f;
                        if (any2 && (cc2 & 1) && X >= sbbs[8] && X < sbbs[9]) wgt += 2.f;
                    }
                    acclw += wgt * ad;
                }

                if (i >= 10) {                      // SSIM, output row r0+i-10
                    float mux = 0.f, muy = 0.f, exx = 0.f, eyy = 0.f, exy = 0.f;
#pragma unroll
                    for (int j = 0; j < 11; ++j) {
                        const int s = (i % 11 + 1 + j) % 11;   // compile-time
                        float wj = g[j];
                        mux = fmaf(wj, ring[s][0], mux);
                        muy = fmaf(wj, ring[s][1], muy);
                        exx = fmaf(wj, ring[s][2], exx);
                        eyy = fmaf(wj, ring[s][3], eyy);
                        exy = fmaf(wj, ring[s][4], exy);
                    }
                    float sx  = exx - mux * mux;
                    float sy  = eyy - muy * muy;
                    float sxy = exy - mux * muy;
                    const float C1 = 1e-4f, C2 = 9e-4f;
                    float num = (2.f * mux * muy + C1) * (2.f * sxy + C2);
                    float den = (mux * mux + muy * muy + C1) * (sx + sy + C2);
                    acc += 0.5f * (1.f - num / (den + 1e-8f));
                }
            }
        }

        // write prefetched chunk c+1 into the other buffer
        // (vmcnt wait lands here, after a full chunk of compute)
        if (do_load) {
            float4* row4 = &sbuf[(c + 1) & 1][w][0];
            row4[3 + 2 * l] = make_float4(pf.x, tf.x, pf.y, tf.y);
            row4[4 + 2 * l] = make_float4(pf.z, tf.z, pf.w, tf.w);
        }
        __syncthreads();
    }

    // ---- block reduction + global accumulate + last-block finalize ---------
#pragma unroll
    for (int off = 32; off > 0; off >>= 1) {
        acc   += __shfl_down(acc, off, 64);
        accl1 += __shfl_down(accl1, off, 64);
        acclw += __shfl_down(acclw, off, 64);
    }
    if (l == 0) {
        red[w] = acc; red[4 + w] = accl1; red[8 + w] = acclw;
    }
    __syncthreads();
    if (tid == 0) {
        atomicAdd(&ws[0], (double)red[0] + red[1] + red[2] + red[3]);
        atomicAdd(&ws[1], (double)red[4] + red[5] + red[6] + red[7]);
        atomicAdd(&ws[2], (double)red[8] + red[9] + red[10] + red[11]);
        __threadfence();
        unsigned prev = atomicAdd((unsigned*)&ws[3], 1u);
        if (prev == NBLOCKS - 1) {
            double s0 = atomicAdd(&ws[0], 0.0);
            double s1 = atomicAdd(&ws[1], 0.0);
            double s2 = atomicAdd(&ws[2], 0.0);
            const double denom = (double)NIMG * NCH * HW * HW;
            out[0] = (float)((10.0 * s0 + 10.0 * s1 + 5.0 * s2) / denom);
        }
    }
}

// ---------------------------------------------------------------------------
extern "C" void kernel_launch(void* const* d_in, const int* in_sizes, int n_in,
                              void* d_out, int out_size, void* d_ws, size_t ws_size,
                              hipStream_t stream)
{
    const float* pred   = (const float*)d_in[0];
    const float* target = (const float*)d_in[1];
    const float* lmk    = (const float*)d_in[2];
    float* out  = (float*)d_out;
    double* ws  = (double*)d_ws;

    hipLaunchKernelGGL(zero_ws_kernel, dim3(1), dim3(64), 0, stream, ws);
    hipLaunchKernelGGL(fused_kernel, dim3(NPLANE, NSTRIP), dim3(256), 0, stream,
                       pred, target, lmk, ws, out);
}

// Round 7
// 459.200 us; speedup vs baseline: 4.7525x; 4.7525x over previous
//
#include <hip/hip_runtime.h>
#include <cmath>

#define HW 256
#define NIMG 48
#define NCH 3
#define NPLANE (NIMG * NCH)
#define STRIP 16
#define NSTRIP (HW / STRIP)           // 16
#define NBLOCKS (NPLANE * NSTRIP)     // 2304
#define NITER 26                      // input rows per block (16 out + 10 halo)

// ws doubles: ws[0]=sum dssim, ws[1]=sum |diff|, ws[2]=sum w*|diff|, ws[3]=done ctr
__global__ void zero_ws_kernel(double* ws) {
    if (threadIdx.x < 4) ws[threadIdx.x] = 0.0;
}

// ---------------------------------------------------------------------------
// Fused SSIM + L1 + weighted-L1, whole-strip LDS staging:
//  - one block = 16-row output strip of one (n,c) plane, 26 input rows
//  - ALL 26 rows staged into LDS up front (float2 (p,t) interleaved, 6-col
//    zero pads both sides, 16B-aligned float4 writes) -> exactly 3 barriers
//    per block, compute phase is barrier-free straight-line code
//  - r6 lesson: ring slots MUST be literal constants. Every row body is a
//    macro instantiation ROW(I) with a literal I: ring[(I)%11], guards
//    (I)>=5 etc all constant-fold; ring provably stays in registers.
//  - separable 11x11: h-conv reads ds_read_b64 (2-way bank alias = free),
//    v-conv via 11-slot register ring, slot (I+1+j)%11 all literal
//  - polygon crossings precomputed per (out-row, edge) in sxc; bbox/valid
//    kept in registers; last finishing block computes the final scalar
// ---------------------------------------------------------------------------
__launch_bounds__(256, 2)
__global__ void fused_kernel(const float* __restrict__ pred,
                             const float* __restrict__ target,
                             const float* __restrict__ lmk,
                             double* __restrict__ ws,
                             float* __restrict__ out)
{
    const int plane = blockIdx.x;          // n*3 + c
    const int n     = plane / 3;
    const int r0    = blockIdx.y * STRIP;
    const int tid   = threadIdx.x;
    const int w     = tid >> 6;            // wave id
    const int l     = tid & 63;            // lane

    // row layout (float2 view, width 268): [0..5]=zero pad (cols -6..-1),
    // [6..261]=cols 0..255, [262..267]=zero pad (cols 256..261).
    // col x, tap k -> float2 index 1 + x + k   (k=0..10)
    __shared__ float4 sbuf4[NITER][134];
    __shared__ float  sxc[STRIP][24];      // crossing x per (out row, edge)
    __shared__ float  slm[48];
    __shared__ float  sbbs[12];
    __shared__ float  svalids[3];
    __shared__ float  red[12];

    // Gaussian weights (same fp32 math as reference)
    float g[11];
    {
        float gs = 0.f;
#pragma unroll
        for (int i = 0; i < 11; ++i) {
            float c = (float)i - 5.0f;
            g[i] = expf(-c * c / 4.5f);
            gs += g[i];
        }
#pragma unroll
        for (int i = 0; i < 11; ++i) g[i] /= gs;
    }

    const float* __restrict__ pp = pred   + (size_t)plane * (HW * HW);
    const float* __restrict__ tp = target + (size_t)plane * (HW * HW);

    // ---- prologue: landmarks + pads + whole-strip staging ------------------
    if (tid < 48) slm[tid] = lmk[n * 136 + 72 + tid];

    // zero the 12 pad float2 per row (26*12 = 312 items)
#pragma unroll
    for (int u = 0; u < 2; ++u) {
        int idx = tid + 256 * u;
        if (idx < NITER * 12) {
            int row = idx / 12, p = idx - row * 12;
            int j = (p < 6) ? p : (256 + p);
            ((float2*)&sbuf4[row][0])[j] = make_float2(0.f, 0.f);
        }
    }

    // stage all 26 rows: 26*64 = 1664 float4-quads, 7 passes
#pragma unroll
    for (int u = 0; u < 7; ++u) {
        int idx = tid + 256 * u;
        if (idx < NITER * 64) {
            int row = idx >> 6, q = idx & 63;
            int r = r0 - 5 + row;
            float4 pf = make_float4(0.f, 0.f, 0.f, 0.f);
            float4 tf = make_float4(0.f, 0.f, 0.f, 0.f);
            if ((unsigned)r < (unsigned)HW) {
                pf = ((const float4*)(pp + (size_t)r * HW))[q];
                tf = ((const float4*)(tp + (size_t)r * HW))[q];
            }
            sbuf4[row][3 + 2 * q] = make_float4(pf.x, tf.x, pf.y, tf.y);
            sbuf4[row][4 + 2 * q] = make_float4(pf.z, tf.z, pf.w, tf.w);
        }
    }
    __syncthreads();   // slm + staging visible

    // bbox + validity per polygon
    if (tid < 3) {
        const int s0 = (tid == 0) ? 0 : (tid == 1) ? 6 : 12;
        const int L  = (tid == 2) ? 12 : 6;
        float xmn = 3e38f, xmx = -3e38f, ymn = 3e38f, ymx = -3e38f;
        for (int i = 0; i < L; ++i) {
            float px = slm[2 * (s0 + i)], py = slm[2 * (s0 + i) + 1];
            xmn = fminf(xmn, px); xmx = fmaxf(xmx, px);
            ymn = fminf(ymn, py); ymx = fmaxf(ymx, py);
        }
        xmn = floorf(xmn); xmx = floorf(xmx); ymn = floorf(ymn); ymx = floorf(ymx);
        sbbs[4 * tid + 0] = xmn; sbbs[4 * tid + 1] = xmx;
        sbbs[4 * tid + 2] = ymn; sbbs[4 * tid + 3] = ymx;
        svalids[tid] = (xmn >= 0.f && ymn >= 0.f && xmx < 256.f && ymx < 256.f) ? 1.f : 0.f;
    }

    // crossing table: STRIP*24 = 384 items
#pragma unroll
    for (int u = 0; u < 2; ++u) {
        int idx = tid + 256 * u;
        if (idx < STRIP * 24) {
            int r = idx / 24, e = idx - r * 24;
            float Y = (float)(r0 + r);
            const int s0 = (e < 6) ? 0 : (e < 12) ? 6 : 12;
            const int L  = (e < 12) ? 6 : 12;
            int il = e - s0;
            int i2 = (il + 1 == L) ? 0 : il + 1;
            float x1 = slm[2 * (s0 + il)], y1 = slm[2 * (s0 + il) + 1];
            float x2 = slm[2 * (s0 + i2)], y2 = slm[2 * (s0 + i2) + 1];
            bool crossing = (y1 > Y) != (y2 > Y);
            // exact reference fp32 expression order
            float xc = (x2 - x1) * (Y - y1) / (y2 - y1 + 1e-6f) + x1;
            sxc[r][e] = crossing ? xc : -3e38f;
        }
    }
    __syncthreads();   // sbbs/svalids/sxc visible

    float bb[12], sv[3];
#pragma unroll
    for (int q = 0; q < 12; ++q) bb[q] = sbbs[q];
#pragma unroll
    for (int q = 0; q < 3; ++q) sv[q] = svalids[q];

    // ---- compute phase: 26 macro-instantiated rows, zero barriers ----------
    float ring[11][5];
#pragma unroll
    for (int s = 0; s < 11; ++s)
#pragma unroll
        for (int q = 0; q < 5; ++q) ring[s][q] = 0.f;

    float acc = 0.f, accl1 = 0.f, acclw = 0.f;
    const float X = (float)tid;

#define ROW(I)                                                                  \
    {                                                                           \
        const float2* row2 = (const float2*)&sbuf4[(I)][0];                     \
        float h0 = 0.f, h1 = 0.f, h2 = 0.f, h3 = 0.f, h4 = 0.f;                 \
        float2 center = make_float2(0.f, 0.f);                                  \
        _Pragma("unroll")                                                       \
        for (int k = 0; k < 11; ++k) {                                          \
            float2 v = row2[1 + tid + k];                                       \
            if (k == 5) center = v;                                             \
            float wk = g[k];                                                    \
            float wp = wk * v.x, wt = wk * v.y;                                 \
            h0 += wp; h1 += wt;                                                 \
            h2 = fmaf(wp, v.x, h2);                                             \
            h3 = fmaf(wt, v.y, h3);                                             \
            h4 = fmaf(wp, v.y, h4);                                             \
        }                                                                       \
        ring[(I) % 11][0] = h0; ring[(I) % 11][1] = h1; ring[(I) % 11][2] = h2; \
        ring[(I) % 11][3] = h3; ring[(I) % 11][4] = h4;                         \
        if ((I) >= 5 && (I) < 5 + STRIP) {                                      \
            float ad = fabsf(center.x - center.y);                              \
            accl1 += ad;                                                        \
            float Y = (float)(r0 + (I) - 5);                                    \
            float wgt = 1.f;                                                    \
            bool any0 = (sv[0] != 0.f) && (Y >= bb[2])  && (Y < bb[3]);         \
            bool any1 = (sv[1] != 0.f) && (Y >= bb[6])  && (Y < bb[7]);         \
            bool any2 = (sv[2] != 0.f) && (Y >= bb[10]) && (Y < bb[11]);        \
            if (any0 || any1 || any2) {                                         \
                const float* xc = sxc[(I) - 5];                                 \
                int cc0 = 0, cc1 = 0, cc2 = 0;                                  \
                _Pragma("unroll")                                               \
                for (int e = 0; e < 6; ++e)   cc0 += (X < xc[e]) ? 1 : 0;       \
                _Pragma("unroll")                                               \
                for (int e = 6; e < 12; ++e)  cc1 += (X < xc[e]) ? 1 : 0;       \
                _Pragma("unroll")                                               \
                for (int e = 12; e < 24; ++e) cc2 += (X < xc[e]) ? 1 : 0;       \
                if (any0 && (cc0 & 1) && X >= bb[0] && X < bb[1]) wgt += 3.f;   \
                if (any1 && (cc1 & 1) && X >= bb[4] && X < bb[5]) wgt += 3.f;   \
                if (any2 && (cc2 & 1) && X >= bb[8] && X < bb[9]) wgt += 2.f;   \
            }                                                                   \
            acclw += wgt * ad;                                                  \
        }                                                                       \
        if ((I) >= 10) {                                                        \
            float mux = 0.f, muy = 0.f, exx = 0.f, eyy = 0.f, exy = 0.f;        \
            _Pragma("unroll")                                                   \
            for (int j = 0; j < 11; ++j) {                                      \
                const int s = ((I) + 1 + j) % 11;    /* literal */              \
                float wj = g[j];                                                \
                mux = fmaf(wj, ring[s][0], mux);                                \
                muy = fmaf(wj, ring[s][1], muy);                                \
                exx = fmaf(wj, ring[s][2], exx);                                \
                eyy = fmaf(wj, ring[s][3], eyy);                                \
                exy = fmaf(wj, ring[s][4], exy);                                \
            }                                                                   \
            float sx  = exx - mux * mux;                                        \
            float sy  = eyy - muy * muy;                                        \
            float sxy = exy - mux * muy;                                        \
            const float C1 = 1e-4f, C2 = 9e-4f;                                 \
            float num = (2.f * mux * muy + C1) * (2.f * sxy + C2);              \
            float den = (mux * mux + muy * muy + C1) * (sx + sy + C2);          \
            acc += 0.5f * (1.f - num / (den + 1e-8f));                          \
        }                                                                       \
    }

    ROW(0)  ROW(1)  ROW(2)  ROW(3)  ROW(4)  ROW(5)  ROW(6)  ROW(7)
    ROW(8)  ROW(9)  ROW(10) ROW(11) ROW(12) ROW(13) ROW(14) ROW(15)
    ROW(16) ROW(17) ROW(18) ROW(19) ROW(20) ROW(21) ROW(22) ROW(23)
    ROW(24) ROW(25)
#undef ROW

    // ---- block reduction + global accumulate + last-block finalize ---------
#pragma unroll
    for (int off = 32; off > 0; off >>= 1) {
        acc   += __shfl_down(acc, off, 64);
        accl1 += __shfl_down(accl1, off, 64);
        acclw += __shfl_down(acclw, off, 64);
    }
    if (l == 0) {
        red[w] = acc; red[4 + w] = accl1; red[8 + w] = acclw;
    }
    __syncthreads();
    if (tid == 0) {
        atomicAdd(&ws[0], (double)red[0] + red[1] + red[2] + red[3]);
        atomicAdd(&ws[1], (double)red[4] + red[5] + red[6] + red[7]);
        atomicAdd(&ws[2], (double)red[8] + red[9] + red[10] + red[11]);
        __threadfence();
        unsigned prev = atomicAdd((unsigned*)&ws[3], 1u);
        if (prev == NBLOCKS - 1) {
            double s0 = atomicAdd(&ws[0], 0.0);
            double s1 = atomicAdd(&ws[1], 0.0);
            double s2 = atomicAdd(&ws[2], 0.0);
            const double denom = (double)NIMG * NCH * HW * HW;
            out[0] = (float)((10.0 * s0 + 10.0 * s1 + 5.0 * s2) / denom);
        }
    }
}

// ---------------------------------------------------------------------------
extern "C" void kernel_launch(void* const* d_in, const int* in_sizes, int n_in,
                              void* d_out, int out_size, void* d_ws, size_t ws_size,
                              hipStream_t stream)
{
    const float* pred   = (const float*)d_in[0];
    const float* target = (const float*)d_in[1];
    const float* lmk    = (const float*)d_in[2];
    float* out  = (float*)d_out;
    double* ws  = (double*)d_ws;

    hipLaunchKernelGGL(zero_ws_kernel, dim3(1), dim3(64), 0, stream, ws);
    hipLaunchKernelGGL(fused_kernel, dim3(NPLANE, NSTRIP), dim3(256), 0, stream,
                       pred, target, lmk, ws, out);
}